// Round 1
// baseline (236.111 us; speedup 1.0000x reference)
//
#include <hip/hip_runtime.h>

// ---------------------------------------------------------------------------
// Fused attention block for MI355X (gfx950).
// Pipeline: split-cast -> GEMM1 (split-bf16 MFMA, epilogue scatters q/k/gate
// f32 + V^T bf16) -> LN+RoPE -> flash attention (bf16 MFMA, fp32 softmax)
// -> gate+split -> GEMM2 (split-bf16 MFMA) -> d_out (f32).
//
// MFMA 16x16x32_bf16 layout assumptions (documented for future rounds):
//   A-frag: lane l holds A[row=l&15][k=8*(l>>4)+j], j=0..7  (consecutive k)
//   B-frag: lane l holds B[k=8*(l>>4)+j][col=l&15]
//   C/D  : lane l reg r -> D[row=4*(l>>4)+r][col=l&15]   (HW-verified)
// LDS swizzle: byte ^= ((row&7)<<4); staging pre-swizzles the GLOBAL source
// so global_load_lds' linear dest + swizzled reads are consistent.
// ---------------------------------------------------------------------------

typedef unsigned short u16;
typedef __bf16 bf16x8 __attribute__((ext_vector_type(8)));
typedef float  f32x4  __attribute__((ext_vector_type(4)));

#define MFMA16(a, b, c) __builtin_amdgcn_mfma_f32_16x16x32_bf16((a), (b), (c), 0, 0, 0)

__device__ __forceinline__ u16 f2bf(float f) {
  unsigned u = __float_as_uint(f);
  return (u16)((u + 0x7FFFu + ((u >> 16) & 1u)) >> 16);   // RNE
}
__device__ __forceinline__ float bf2f(u16 h) {
  return __uint_as_float(((unsigned)h) << 16);
}
__device__ __forceinline__ void gload16(const void* g, void* l) {
  __builtin_amdgcn_global_load_lds(
      (const __attribute__((address_space(1))) void*)g,
      (__attribute__((address_space(3))) void*)l, 16, 0, 0);
}

// ---------------------------------------------------------------------------
// Small helper kernels
// ---------------------------------------------------------------------------
__global__ void rope_table_kernel(const float* __restrict__ freqs, float* __restrict__ tbl) {
  int i = blockIdx.x * 256 + threadIdx.x;           // 2048*32
  if (i >= 2048 * 32) return;
  int s = i >> 5, j = i & 31;
  float f = freqs[i];
  tbl[s * 64 + j]      = cosf(f);
  tbl[s * 64 + 32 + j] = sinf(f);
}

__global__ void split_cast_kernel(const float* __restrict__ in, u16* __restrict__ hi,
                                  u16* __restrict__ lo, int n4) {
  int i = blockIdx.x * 256 + threadIdx.x;
  if (i >= n4) return;
  float4 v = ((const float4*)in)[i];
  ushort4 H, L;
  H.x = f2bf(v.x); L.x = f2bf(v.x - bf2f(H.x));
  H.y = f2bf(v.y); L.y = f2bf(v.y - bf2f(H.y));
  H.z = f2bf(v.z); L.z = f2bf(v.z - bf2f(H.z));
  H.w = f2bf(v.w); L.w = f2bf(v.w - bf2f(H.w));
  ((ushort4*)hi)[i] = H;
  ((ushort4*)lo)[i] = L;
}

// in [R][C] f32 -> out [C][R] bf16 hi/lo  (transpose + split)
__global__ void split_transpose_kernel(const float* __restrict__ in, u16* __restrict__ oh,
                                       u16* __restrict__ ol, int R, int C) {
  __shared__ float t[64][65];
  int c0 = blockIdx.x * 64, r0 = blockIdx.y * 64;
  int tx = threadIdx.x & 15, ty = threadIdx.x >> 4;
#pragma unroll
  for (int i = 0; i < 4; ++i) {
    float4 v = *(const float4*)&in[(size_t)(r0 + ty + 16 * i) * C + c0 + tx * 4];
    t[ty + 16 * i][tx * 4 + 0] = v.x;
    t[ty + 16 * i][tx * 4 + 1] = v.y;
    t[ty + 16 * i][tx * 4 + 2] = v.z;
    t[ty + 16 * i][tx * 4 + 3] = v.w;
  }
  __syncthreads();
#pragma unroll
  for (int i = 0; i < 4; ++i) {
    int n = c0 + ty + 16 * i;
    int k = r0 + tx * 4;
    ushort4 H, L;
    float a0 = t[tx * 4 + 0][ty + 16 * i];
    float a1 = t[tx * 4 + 1][ty + 16 * i];
    float a2 = t[tx * 4 + 2][ty + 16 * i];
    float a3 = t[tx * 4 + 3][ty + 16 * i];
    H.x = f2bf(a0); L.x = f2bf(a0 - bf2f(H.x));
    H.y = f2bf(a1); L.y = f2bf(a1 - bf2f(H.y));
    H.z = f2bf(a2); L.z = f2bf(a2 - bf2f(H.z));
    H.w = f2bf(a3); L.w = f2bf(a3 - bf2f(H.w));
    *(ushort4*)&oh[(size_t)n * R + k] = H;
    *(ushort4*)&ol[(size_t)n * R + k] = L;
  }
}

__global__ void fill_debug_kernel(float* out, int n) {
  int i = blockIdx.x * 256 + threadIdx.x;
  if (i < n) out[i] = 12345.0f;
}

// ---------------------------------------------------------------------------
// Split-bf16 GEMM: C[M,N] = A[M,K] @ B[K,N], B given TRANSPOSED ([N][K]).
// A = Ah+Al, B = Bh+Bl; computes AhBh + AhBl + AlBh (fp32-class accuracy).
// EPI==0: plain f32 C.  EPI==1: qkv epilogue (q/k/gate f32, v -> V^T bf16).
// ---------------------------------------------------------------------------
template <int EPI>
__global__ __launch_bounds__(256, 2) void gemm_split(
    const u16* __restrict__ Ah, const u16* __restrict__ Al,
    const u16* __restrict__ Bh, const u16* __restrict__ Bl,
    float* __restrict__ Cout, int M, int N, int K,
    float* __restrict__ q_f32, float* __restrict__ k_f32,
    float* __restrict__ gate_f32, u16* __restrict__ v_t) {
  __shared__ u16 sAh[128 * 64], sAl[128 * 64], sBh[128 * 64], sBl[128 * 64];
  const int tid = threadIdx.x, lane = tid & 63;
  const int wave = tid >> 6, wm = wave >> 1, wn = wave & 1;
  const int lg = lane >> 4, lr = lane & 15;
  const int n0 = blockIdx.x * 128, m0 = blockIdx.y * 128;

  f32x4 acc[4][4];
#pragma unroll
  for (int m = 0; m < 4; ++m)
#pragma unroll
    for (int n = 0; n < 4; ++n) acc[m][n] = (f32x4){0.f, 0.f, 0.f, 0.f};

  for (int k0 = 0; k0 < K; k0 += 64) {
#pragma unroll
    for (int r = 0; r < 4; ++r) {
      int off = (tid + r * 256) * 16;               // byte offset in 16KB tile
      int row = off >> 7;                           // 128B rows
      int col = ((off & 127) ^ ((row & 7) << 4)) >> 1;  // pre-swizzled source col
      size_t ga = (size_t)(m0 + row) * K + k0 + col;
      size_t gb = (size_t)(n0 + row) * K + k0 + col;
      gload16(Ah + ga, (char*)sAh + off);
      gload16(Al + ga, (char*)sAl + off);
      gload16(Bh + gb, (char*)sBh + off);
      gload16(Bl + gb, (char*)sBl + off);
    }
    __syncthreads();
#pragma unroll
    for (int ks = 0; ks < 2; ++ks) {
      bf16x8 bh[4], bl[4];
#pragma unroll
      for (int n = 0; n < 4; ++n) {
        int row = wn * 64 + n * 16 + lr;
        int boff = (row << 7) + (ks << 6) + (lg << 4);
        boff ^= (row & 7) << 4;
        bh[n] = *(const bf16x8*)((const char*)sBh + boff);
        bl[n] = *(const bf16x8*)((const char*)sBl + boff);
      }
#pragma unroll
      for (int m = 0; m < 4; ++m) {
        int row = wm * 64 + m * 16 + lr;
        int aoff = (row << 7) + (ks << 6) + (lg << 4);
        aoff ^= (row & 7) << 4;
        bf16x8 ah = *(const bf16x8*)((const char*)sAh + aoff);
        bf16x8 al = *(const bf16x8*)((const char*)sAl + aoff);
#pragma unroll
        for (int n = 0; n < 4; ++n) {
          acc[m][n] = MFMA16(ah, bh[n], acc[m][n]);
          acc[m][n] = MFMA16(ah, bl[n], acc[m][n]);
          acc[m][n] = MFMA16(al, bh[n], acc[m][n]);
        }
      }
    }
    __syncthreads();
  }

  if (EPI == 0) {
#pragma unroll
    for (int m = 0; m < 4; ++m) {
      int row = m0 + wm * 64 + m * 16 + 4 * lg;
#pragma unroll
      for (int n = 0; n < 4; ++n) {
        int col = n0 + wn * 64 + n * 16 + lr;
#pragma unroll
        for (int r = 0; r < 4; ++r) Cout[(size_t)(row + r) * N + col] = acc[m][n][r];
      }
    }
  } else {
    int region = n0 >> 10;  // 0:q 1:k 2:v 3:gate
#pragma unroll
    for (int m = 0; m < 4; ++m) {
      int row = m0 + wm * 64 + m * 16 + 4 * lg;
#pragma unroll
      for (int n = 0; n < 4; ++n) {
        int col = n0 + wn * 64 + n * 16 + lr;
        if (region == 0) {
#pragma unroll
          for (int r = 0; r < 4; ++r) q_f32[(size_t)(row + r) * 1024 + col] = acc[m][n][r];
        } else if (region == 1) {
#pragma unroll
          for (int r = 0; r < 4; ++r) k_f32[(size_t)(row + r) * 1024 + col - 1024] = acc[m][n][r];
        } else if (region == 3) {
#pragma unroll
          for (int r = 0; r < 4; ++r) gate_f32[(size_t)(row + r) * 1024 + col - 3072] = acc[m][n][r];
        } else {
          int c = col - 2048, hh = c >> 6, d = c & 63;
          int b = row >> 11, s = row & 2047;
          ushort4 pv;
          pv.x = f2bf(acc[m][n][0]);
          pv.y = f2bf(acc[m][n][1]);
          pv.z = f2bf(acc[m][n][2]);
          pv.w = f2bf(acc[m][n][3]);
          *(ushort4*)&v_t[(size_t)((b * 16 + hh) * 64 + d) * 2048 + s] = pv;
        }
      }
    }
  }
}

// ---------------------------------------------------------------------------
// Per-head LayerNorm + RoPE, f32 in -> bf16 out. 1 block = 1 (b,s) row.
// 16 threads per head (4 elems each); head-dim reduce via shfl_xor(1,2,4,8).
// ---------------------------------------------------------------------------
__global__ void norm_rope_kernel(const float* __restrict__ qf, const float* __restrict__ kf,
                                 const float* __restrict__ tbl,
                                 const float* __restrict__ qn_w, const float* __restrict__ qn_b,
                                 const float* __restrict__ kn_w, const float* __restrict__ kn_b,
                                 u16* __restrict__ q_b, u16* __restrict__ k_b) {
  int row = blockIdx.x;
  int s = row & 2047;
  int hh = threadIdx.x >> 4, sub = threadIdx.x & 15;
  int base = row * 1024 + hh * 64 + sub * 4;
  float c0 = tbl[s * 64 + sub * 2 + 0], c1 = tbl[s * 64 + sub * 2 + 1];
  float s0 = tbl[s * 64 + 32 + sub * 2 + 0], s1 = tbl[s * 64 + 32 + sub * 2 + 1];
#pragma unroll
  for (int which = 0; which < 2; ++which) {
    const float* src = which ? kf : qf;
    const float* wp = which ? kn_w : qn_w;
    const float* bp = which ? kn_b : qn_b;
    u16* dst = which ? k_b : q_b;
    float4 x = *(const float4*)&src[base];
    float sum = x.x + x.y + x.z + x.w;
    sum += __shfl_xor(sum, 1); sum += __shfl_xor(sum, 2);
    sum += __shfl_xor(sum, 4); sum += __shfl_xor(sum, 8);
    float mu = sum * (1.0f / 64.0f);
    float d0 = x.x - mu, d1 = x.y - mu, d2 = x.z - mu, d3 = x.w - mu;
    float sq = d0 * d0 + d1 * d1 + d2 * d2 + d3 * d3;
    sq += __shfl_xor(sq, 1); sq += __shfl_xor(sq, 2);
    sq += __shfl_xor(sq, 4); sq += __shfl_xor(sq, 8);
    float rstd = rsqrtf(sq * (1.0f / 64.0f) + 1e-5f);
    float4 w = *(const float4*)&wp[sub * 4];
    float4 bb = *(const float4*)&bp[sub * 4];
    float n0 = d0 * rstd * w.x + bb.x;
    float n1 = d1 * rstd * w.y + bb.y;
    float n2 = d2 * rstd * w.z + bb.z;
    float n3 = d3 * rstd * w.w + bb.w;
    float r0 = n0 * c0 - n1 * s0, r1 = n0 * s0 + n1 * c0;
    float r2 = n2 * c1 - n3 * s1, r3 = n2 * s1 + n3 * c1;
    ushort4 ov;
    ov.x = f2bf(r0); ov.y = f2bf(r1); ov.z = f2bf(r2); ov.w = f2bf(r3);
    *(ushort4*)&dst[base] = ov;
  }
}

// ---------------------------------------------------------------------------
// Flash attention. Block = (b, h, 128-q-tile); wave = 32 q rows.
// Swapped QK^T: st = K·Q^T so softmax is a per-column (2 shfl) reduction.
// P^T staged per-wave in LDS (swizzled) -> PV computes O^T = V^T @ P^T.
// ---------------------------------------------------------------------------
__global__ __launch_bounds__(256, 2) void attn_kernel(const u16* __restrict__ q_b,
                                                      const u16* __restrict__ k_b,
                                                      const u16* __restrict__ v_t,
                                                      float* __restrict__ o) {
  __shared__ u16 sK[128 * 64];     // [kv][64 d], 128B rows, swizzled
  __shared__ u16 sV[64 * 128];     // [d][128 kv], 256B rows, swizzled
  __shared__ u16 sP[4][32 * 128];  // per wave: [q][kv], 256B rows, swizzled
  const int tid = threadIdx.x, lane = tid & 63, wave = tid >> 6;
  const int lg = lane >> 4, lr = lane & 15;
  const int bh = blockIdx.x >> 4, qt = blockIdx.x & 15;
  const int b = bh >> 4, h = bh & 15;
  const int qrow0 = b * 2048 + qt * 128 + wave * 32;

  bf16x8 qf[2][2];
#pragma unroll
  for (int n = 0; n < 2; ++n)
#pragma unroll
    for (int ks = 0; ks < 2; ++ks)
      qf[n][ks] = *(const bf16x8*)&q_b[(size_t)(qrow0 + n * 16 + lr) * 1024 + h * 64 + ks * 32 + lg * 8];

  f32x4 accO[4][2];
#pragma unroll
  for (int m = 0; m < 4; ++m) {
    accO[m][0] = (f32x4){0.f, 0.f, 0.f, 0.f};
    accO[m][1] = (f32x4){0.f, 0.f, 0.f, 0.f};
  }
  float mrun[2] = {-1e30f, -1e30f};
  float lrun[2] = {0.f, 0.f};

  for (int kv0 = 0; kv0 < 2048; kv0 += 128) {
#pragma unroll
    for (int r = 0; r < 4; ++r) {
      int off = (tid + r * 256) * 16;
      {  // K tile
        int row = off >> 7;
        int col = ((off & 127) ^ ((row & 7) << 4)) >> 1;
        gload16(&k_b[(size_t)(b * 2048 + kv0 + row) * 1024 + h * 64 + col], (char*)sK + off);
      }
      {  // V^T tile
        int d = off >> 8;
        int col = ((off & 255) ^ ((d & 7) << 4)) >> 1;
        gload16(&v_t[(size_t)(bh * 64 + d) * 2048 + kv0 + col], (char*)sV + off);
      }
    }
    __syncthreads();

    f32x4 st[8][2];
#pragma unroll
    for (int m = 0; m < 8; ++m) {
      st[m][0] = (f32x4){0.f, 0.f, 0.f, 0.f};
      st[m][1] = (f32x4){0.f, 0.f, 0.f, 0.f};
    }
#pragma unroll
    for (int m = 0; m < 8; ++m)
#pragma unroll
      for (int ks = 0; ks < 2; ++ks) {
        int row = m * 16 + lr;
        int koff = (row << 7) + (ks << 6) + (lg << 4);
        koff ^= (row & 7) << 4;
        bf16x8 a = *(const bf16x8*)((const char*)sK + koff);
        st[m][0] = MFMA16(a, qf[0][ks], st[m][0]);
        st[m][1] = MFMA16(a, qf[1][ks], st[m][1]);
      }

    float fac[2];
#pragma unroll
    for (int n = 0; n < 2; ++n) {
      float vm = -1e30f;
#pragma unroll
      for (int m = 0; m < 8; ++m)
#pragma unroll
        for (int r = 0; r < 4; ++r) vm = fmaxf(vm, st[m][n][r]);
      vm = fmaxf(vm, __shfl_xor(vm, 16));
      vm = fmaxf(vm, __shfl_xor(vm, 32));
      float mnew = fmaxf(mrun[n], vm);
      fac[n] = __expf((mrun[n] - mnew) * 0.125f);
      mrun[n] = mnew;
      float ps = 0.f;
      int q = n * 16 + lr;
#pragma unroll
      for (int m = 0; m < 8; ++m) {
        float p0 = __expf((st[m][n][0] - mnew) * 0.125f);
        float p1 = __expf((st[m][n][1] - mnew) * 0.125f);
        float p2 = __expf((st[m][n][2] - mnew) * 0.125f);
        float p3 = __expf((st[m][n][3] - mnew) * 0.125f);
        ps += p0 + p1 + p2 + p3;
        ushort4 pk;
        pk.x = f2bf(p0); pk.y = f2bf(p1); pk.z = f2bf(p2); pk.w = f2bf(p3);
        int poff = (q << 8) + (m << 5) + (lg << 3);
        poff ^= (q & 7) << 4;
        *(ushort4*)((char*)sP[wave] + poff) = pk;
      }
      ps += __shfl_xor(ps, 16);
      ps += __shfl_xor(ps, 32);
      lrun[n] = lrun[n] * fac[n] + ps;
#pragma unroll
      for (int m = 0; m < 4; ++m) accO[m][n] *= fac[n];
    }
    asm volatile("s_waitcnt lgkmcnt(0)" ::: "memory");
    __builtin_amdgcn_sched_barrier(0);

    bf16x8 pb[2][4];
#pragma unroll
    for (int n = 0; n < 2; ++n) {
      int q = n * 16 + lr;
#pragma unroll
      for (int ks = 0; ks < 4; ++ks) {
        int poff = (q << 8) + (ks << 6) + (lg << 4);
        poff ^= (q & 7) << 4;
        pb[n][ks] = *(const bf16x8*)((const char*)sP[wave] + poff);
      }
    }
#pragma unroll
    for (int m = 0; m < 4; ++m)
#pragma unroll
      for (int ks = 0; ks < 4; ++ks) {
        int d = m * 16 + lr;
        int voff = (d << 8) + (ks << 6) + (lg << 4);
        voff ^= (d & 7) << 4;
        bf16x8 av = *(const bf16x8*)((const char*)sV + voff);
        accO[m][0] = MFMA16(av, pb[0][ks], accO[m][0]);
        accO[m][1] = MFMA16(av, pb[1][ks], accO[m][1]);
      }
    __syncthreads();
  }

#pragma unroll
  for (int n = 0; n < 2; ++n) {
    float rl = 1.0f / lrun[n];
    int orow = qrow0 + n * 16 + lr;
#pragma unroll
    for (int m = 0; m < 4; ++m) {
      f32x4 v = accO[m][n] * rl;
      *(f32x4*)&o[(size_t)orow * 1024 + h * 64 + m * 16 + lg * 4] = v;
    }
  }
}

__global__ void gate_split_kernel(const float* __restrict__ o, const float* __restrict__ g,
                                  u16* __restrict__ hi, u16* __restrict__ lo, int n4) {
  int i = blockIdx.x * 256 + threadIdx.x;
  if (i >= n4) return;
  float4 ov = ((const float4*)o)[i];
  float4 gv = ((const float4*)g)[i];
  float x0 = ov.x / (1.f + __expf(-gv.x));
  float x1 = ov.y / (1.f + __expf(-gv.y));
  float x2 = ov.z / (1.f + __expf(-gv.z));
  float x3 = ov.w / (1.f + __expf(-gv.w));
  ushort4 H, L;
  H.x = f2bf(x0); L.x = f2bf(x0 - bf2f(H.x));
  H.y = f2bf(x1); L.y = f2bf(x1 - bf2f(H.y));
  H.z = f2bf(x2); L.z = f2bf(x2 - bf2f(H.z));
  H.w = f2bf(x3); L.w = f2bf(x3 - bf2f(H.w));
  ((ushort4*)hi)[i] = H;
  ((ushort4*)lo)[i] = L;
}

// ---------------------------------------------------------------------------
extern "C" void kernel_launch(void* const* d_in, const int* in_sizes, int n_in,
                              void* d_out, int out_size, void* d_ws, size_t ws_size,
                              hipStream_t stream) {
  const float* x      = (const float*)d_in[0];
  const float* freqs  = (const float*)d_in[1];
  const float* w_qkv  = (const float*)d_in[2];
  const float* w_out  = (const float*)d_in[3];
  const float* qn_w   = (const float*)d_in[4];
  const float* qn_b   = (const float*)d_in[5];
  const float* kn_w   = (const float*)d_in[6];
  const float* kn_b   = (const float*)d_in[7];
  float* out = (float*)d_out;
  char* ws = (char*)d_ws;
  const size_t MB = 1024 * 1024;
  // ws map (109 MB): see offsets; o_buf aliases wqh/wql (dead after GEMM1),
  // og hi/lo alias xh/xl (dead after GEMM1).
  float* q_f32    = (float*)(ws + 0);
  float* k_f32    = (float*)(ws + 16 * MB);
  float* gate_f32 = (float*)(ws + 32 * MB);
  u16*   v_t      = (u16*)(ws + 48 * MB);
  u16*   xh       = (u16*)(ws + 56 * MB);
  u16*   xl       = (u16*)(ws + 64 * MB);
  u16*   wqh      = (u16*)(ws + 72 * MB);
  u16*   wql      = (u16*)(ws + 80 * MB);
  u16*   woh      = (u16*)(ws + 88 * MB);
  u16*   wol      = (u16*)(ws + 90 * MB);
  u16*   q_b      = (u16*)(ws + 92 * MB);
  u16*   k_b      = (u16*)(ws + 100 * MB);
  float* tbl      = (float*)(ws + 108 * MB);
  float* o_buf    = (float*)(ws + 72 * MB);  // alias: wq dead after GEMM1

  if (ws_size < (size_t)109 * MB) {  // sentinel: signals ws shortfall in absmax
    fill_debug_kernel<<<(out_size + 255) / 256, 256, 0, stream>>>(out, out_size);
    return;
  }

  rope_table_kernel<<<256, 256, 0, stream>>>(freqs, tbl);
  split_cast_kernel<<<4096, 256, 0, stream>>>(x, xh, xl, 1024 * 1024);
  split_transpose_kernel<<<dim3(64, 16), 256, 0, stream>>>(w_qkv, wqh, wql, 1024, 4096);
  split_transpose_kernel<<<dim3(16, 16), 256, 0, stream>>>(w_out, woh, wol, 1024, 1024);

  gemm_split<1><<<dim3(32, 32), 256, 0, stream>>>(xh, xl, wqh, wql, nullptr, 4096, 4096, 1024,
                                                  q_f32, k_f32, gate_f32, v_t);
  norm_rope_kernel<<<4096, 256, 0, stream>>>(q_f32, k_f32, tbl, qn_w, qn_b, kn_w, kn_b, q_b, k_b);
  attn_kernel<<<512, 256, 0, stream>>>(q_b, k_b, v_t, o_buf);
  gate_split_kernel<<<4096, 256, 0, stream>>>(o_buf, gate_f32, xh, xl, 1024 * 1024);
  gemm_split<0><<<dim3(8, 32), 256, 0, stream>>>(xh, xl, woh, wol, out, 4096, 1024, 1024,
                                                 nullptr, nullptr, nullptr, nullptr);
}

// Round 2
// 165.531 us; speedup vs baseline: 1.4264x; 1.4264x over previous
//
#include <hip/hip_runtime.h>

// ---------------------------------------------------------------------------
// Fused attention block for MI355X (gfx950) — round 2: all-fp16 MFMA.
// Pipeline: cast -> GEMM1 (fp16 MFMA; epilogue scatters q/k/gate f32 + V^T
// fp16) -> LN+RoPE -> flash attention (fp16 MFMA, fp32 softmax, fused
// sigmoid-gate epilogue writing fp16) -> GEMM2 (fp16 MFMA) -> d_out f32.
//
// Accuracy budget (validated r1: split-bf16 gave 4.9e-4, thr 2.7e-3):
//   fp16 GEMM2 direct error ~6e-4 max; GEMM1 error paths damped by
//   LN/softmax/averaging/sigmoid'; attn operand error improves 4x vs bf16.
//
// MFMA f32_16x16x32_f16 layout (same as bf16 family, HW-verified r1):
//   A-frag: lane l holds A[row=l&15][k=8*(l>>4)+j]
//   B-frag: lane l holds B[k=8*(l>>4)+j][col=l&15]
//   C/D  : lane l reg r -> D[row=4*(l>>4)+r][col=l&15]
// LDS swizzle: byte ^= ((row&7)<<4); global source pre-swizzled so
// global_load_lds' linear dest + swizzled reads are consistent.
// ---------------------------------------------------------------------------

typedef _Float16 f16;
typedef _Float16 f16x8 __attribute__((ext_vector_type(8)));
typedef _Float16 f16x4 __attribute__((ext_vector_type(4)));
typedef float    f32x4 __attribute__((ext_vector_type(4)));

#define MFMA16(a, b, c) __builtin_amdgcn_mfma_f32_16x16x32_f16((a), (b), (c), 0, 0, 0)

__device__ __forceinline__ void gload16(const void* g, void* l) {
  __builtin_amdgcn_global_load_lds(
      (const __attribute__((address_space(1))) void*)g,
      (__attribute__((address_space(3))) void*)l, 16, 0, 0);
}

// ---------------------------------------------------------------------------
// Helper kernels
// ---------------------------------------------------------------------------
__global__ void rope_table_kernel(const float* __restrict__ freqs, float* __restrict__ tbl) {
  int i = blockIdx.x * 256 + threadIdx.x;  // 2048*32
  if (i >= 2048 * 32) return;
  int s = i >> 5, j = i & 31;
  float f = freqs[i];
  tbl[s * 64 + j]      = cosf(f);
  tbl[s * 64 + 32 + j] = sinf(f);
}

__global__ void cast_f16_kernel(const float* __restrict__ in, f16* __restrict__ out, int n8) {
  int i = blockIdx.x * 256 + threadIdx.x;
  if (i >= n8) return;
  float4 a = ((const float4*)in)[2 * i];
  float4 b = ((const float4*)in)[2 * i + 1];
  f16x8 o;
  o[0] = (f16)a.x; o[1] = (f16)a.y; o[2] = (f16)a.z; o[3] = (f16)a.w;
  o[4] = (f16)b.x; o[5] = (f16)b.y; o[6] = (f16)b.z; o[7] = (f16)b.w;
  ((f16x8*)out)[i] = o;
}

// in [R][C] f32 -> out [C][R] f16 (transpose + cast)
__global__ void transpose_cast_kernel(const float* __restrict__ in, f16* __restrict__ out,
                                      int R, int C) {
  __shared__ float t[64][65];
  int c0 = blockIdx.x * 64, r0 = blockIdx.y * 64;
  int tx = threadIdx.x & 15, ty = threadIdx.x >> 4;
#pragma unroll
  for (int i = 0; i < 4; ++i) {
    float4 v = *(const float4*)&in[(size_t)(r0 + ty + 16 * i) * C + c0 + tx * 4];
    t[ty + 16 * i][tx * 4 + 0] = v.x;
    t[ty + 16 * i][tx * 4 + 1] = v.y;
    t[ty + 16 * i][tx * 4 + 2] = v.z;
    t[ty + 16 * i][tx * 4 + 3] = v.w;
  }
  __syncthreads();
#pragma unroll
  for (int i = 0; i < 4; ++i) {
    int n = c0 + ty + 16 * i;
    int k = r0 + tx * 4;
    f16x4 o;
    o[0] = (f16)t[tx * 4 + 0][ty + 16 * i];
    o[1] = (f16)t[tx * 4 + 1][ty + 16 * i];
    o[2] = (f16)t[tx * 4 + 2][ty + 16 * i];
    o[3] = (f16)t[tx * 4 + 3][ty + 16 * i];
    *(f16x4*)&out[(size_t)n * R + k] = o;
  }
}

__global__ void fill_debug_kernel(float* out, int n) {
  int i = blockIdx.x * 256 + threadIdx.x;
  if (i < n) out[i] = 12345.0f;
}

// ---------------------------------------------------------------------------
// fp16 GEMM: C[M,N] = A[M,K] @ B[K,N], B given TRANSPOSED ([N][K]).
// EPI==0: plain f32 C.  EPI==1: qkv epilogue (q/k/gate f32, v -> V^T fp16).
// ---------------------------------------------------------------------------
template <int EPI>
__global__ __launch_bounds__(256, 2) void gemm_f16(
    const f16* __restrict__ A, const f16* __restrict__ B,
    float* __restrict__ Cout, int M, int N, int K,
    float* __restrict__ q_f32, float* __restrict__ k_f32,
    float* __restrict__ gate_f32, f16* __restrict__ v_t) {
  __shared__ f16 sA[128 * 64], sB[128 * 64];
  const int tid = threadIdx.x, lane = tid & 63;
  const int wave = tid >> 6, wm = wave >> 1, wn = wave & 1;
  const int lg = lane >> 4, lr = lane & 15;
  const int n0 = blockIdx.x * 128, m0 = blockIdx.y * 128;

  f32x4 acc[4][4];
#pragma unroll
  for (int m = 0; m < 4; ++m)
#pragma unroll
    for (int n = 0; n < 4; ++n) acc[m][n] = (f32x4){0.f, 0.f, 0.f, 0.f};

  for (int k0 = 0; k0 < K; k0 += 64) {
#pragma unroll
    for (int r = 0; r < 4; ++r) {
      int off = (tid + r * 256) * 16;                   // byte offset in 16KB tile
      int row = off >> 7;                               // 128B rows
      int col = ((off & 127) ^ ((row & 7) << 4)) >> 1;  // pre-swizzled source col
      gload16(A + (size_t)(m0 + row) * K + k0 + col, (char*)sA + off);
      gload16(B + (size_t)(n0 + row) * K + k0 + col, (char*)sB + off);
    }
    __syncthreads();
#pragma unroll
    for (int ks = 0; ks < 2; ++ks) {
      f16x8 bfr[4];
#pragma unroll
      for (int n = 0; n < 4; ++n) {
        int row = wn * 64 + n * 16 + lr;
        int boff = (row << 7) + (ks << 6) + (lg << 4);
        boff ^= (row & 7) << 4;
        bfr[n] = *(const f16x8*)((const char*)sB + boff);
      }
#pragma unroll
      for (int m = 0; m < 4; ++m) {
        int row = wm * 64 + m * 16 + lr;
        int aoff = (row << 7) + (ks << 6) + (lg << 4);
        aoff ^= (row & 7) << 4;
        f16x8 afr = *(const f16x8*)((const char*)sA + aoff);
#pragma unroll
        for (int n = 0; n < 4; ++n) acc[m][n] = MFMA16(afr, bfr[n], acc[m][n]);
      }
    }
    __syncthreads();
  }

  if (EPI == 0) {
#pragma unroll
    for (int m = 0; m < 4; ++m) {
      int row = m0 + wm * 64 + m * 16 + 4 * lg;
#pragma unroll
      for (int n = 0; n < 4; ++n) {
        int col = n0 + wn * 64 + n * 16 + lr;
#pragma unroll
        for (int r = 0; r < 4; ++r) Cout[(size_t)(row + r) * N + col] = acc[m][n][r];
      }
    }
  } else {
    int region = n0 >> 10;  // 0:q 1:k 2:v 3:gate
#pragma unroll
    for (int m = 0; m < 4; ++m) {
      int row = m0 + wm * 64 + m * 16 + 4 * lg;
#pragma unroll
      for (int n = 0; n < 4; ++n) {
        int col = n0 + wn * 64 + n * 16 + lr;
        if (region == 0) {
#pragma unroll
          for (int r = 0; r < 4; ++r) q_f32[(size_t)(row + r) * 1024 + col] = acc[m][n][r];
        } else if (region == 1) {
#pragma unroll
          for (int r = 0; r < 4; ++r) k_f32[(size_t)(row + r) * 1024 + col - 1024] = acc[m][n][r];
        } else if (region == 3) {
#pragma unroll
          for (int r = 0; r < 4; ++r) gate_f32[(size_t)(row + r) * 1024 + col - 3072] = acc[m][n][r];
        } else {
          int c = col - 2048, hh = c >> 6, d = c & 63;
          int b = row >> 11, s = row & 2047;
          f16x4 pv;
          pv[0] = (f16)acc[m][n][0];
          pv[1] = (f16)acc[m][n][1];
          pv[2] = (f16)acc[m][n][2];
          pv[3] = (f16)acc[m][n][3];
          *(f16x4*)&v_t[(size_t)((b * 16 + hh) * 64 + d) * 2048 + s] = pv;
        }
      }
    }
  }
}

// ---------------------------------------------------------------------------
// Per-head LayerNorm + RoPE, f32 in -> fp16 out. 1 block = 1 (b,s) row.
// ---------------------------------------------------------------------------
__global__ void norm_rope_kernel(const float* __restrict__ qf, const float* __restrict__ kf,
                                 const float* __restrict__ tbl,
                                 const float* __restrict__ qn_w, const float* __restrict__ qn_b,
                                 const float* __restrict__ kn_w, const float* __restrict__ kn_b,
                                 f16* __restrict__ q_h, f16* __restrict__ k_h) {
  int row = blockIdx.x;
  int s = row & 2047;
  int hh = threadIdx.x >> 4, sub = threadIdx.x & 15;
  int base = row * 1024 + hh * 64 + sub * 4;
  float c0 = tbl[s * 64 + sub * 2 + 0], c1 = tbl[s * 64 + sub * 2 + 1];
  float s0 = tbl[s * 64 + 32 + sub * 2 + 0], s1 = tbl[s * 64 + 32 + sub * 2 + 1];
#pragma unroll
  for (int which = 0; which < 2; ++which) {
    const float* src = which ? kf : qf;
    const float* wp = which ? kn_w : qn_w;
    const float* bp = which ? kn_b : qn_b;
    f16* dst = which ? k_h : q_h;
    float4 x = *(const float4*)&src[base];
    float sum = x.x + x.y + x.z + x.w;
    sum += __shfl_xor(sum, 1); sum += __shfl_xor(sum, 2);
    sum += __shfl_xor(sum, 4); sum += __shfl_xor(sum, 8);
    float mu = sum * (1.0f / 64.0f);
    float d0 = x.x - mu, d1 = x.y - mu, d2 = x.z - mu, d3 = x.w - mu;
    float sq = d0 * d0 + d1 * d1 + d2 * d2 + d3 * d3;
    sq += __shfl_xor(sq, 1); sq += __shfl_xor(sq, 2);
    sq += __shfl_xor(sq, 4); sq += __shfl_xor(sq, 8);
    float rstd = rsqrtf(sq * (1.0f / 64.0f) + 1e-5f);
    float4 w = *(const float4*)&wp[sub * 4];
    float4 bb = *(const float4*)&bp[sub * 4];
    float n0 = d0 * rstd * w.x + bb.x;
    float n1 = d1 * rstd * w.y + bb.y;
    float n2 = d2 * rstd * w.z + bb.z;
    float n3 = d3 * rstd * w.w + bb.w;
    float r0 = n0 * c0 - n1 * s0, r1 = n0 * s0 + n1 * c0;
    float r2 = n2 * c1 - n3 * s1, r3 = n2 * s1 + n3 * c1;
    f16x4 ov;
    ov[0] = (f16)r0; ov[1] = (f16)r1; ov[2] = (f16)r2; ov[3] = (f16)r3;
    *(f16x4*)&dst[base] = ov;
  }
}

// ---------------------------------------------------------------------------
// Flash attention + fused sigmoid-gate epilogue (fp16 out = GEMM2 A operand).
// Block = (b, h, 128-q-tile); wave = 32 q rows.  Swapped QK^T (st = K.Q^T).
// ---------------------------------------------------------------------------
__global__ __launch_bounds__(256, 2) void attn_kernel(const f16* __restrict__ q_h,
                                                      const f16* __restrict__ k_h,
                                                      const f16* __restrict__ v_t,
                                                      const float* __restrict__ gate_f32,
                                                      f16* __restrict__ a16) {
  __shared__ f16 sK[128 * 64];     // [kv][64 d], 128B rows, swizzled
  __shared__ f16 sV[64 * 128];     // [d][128 kv], 256B rows, swizzled
  __shared__ f16 sP[4][32 * 128];  // per wave: [q][kv], 256B rows, swizzled
  const int tid = threadIdx.x, lane = tid & 63, wave = tid >> 6;
  const int lg = lane >> 4, lr = lane & 15;
  const int bh = blockIdx.x >> 4, qt = blockIdx.x & 15;
  const int b = bh >> 4, h = bh & 15;
  const int qrow0 = b * 2048 + qt * 128 + wave * 32;

  f16x8 qf[2][2];
#pragma unroll
  for (int n = 0; n < 2; ++n)
#pragma unroll
    for (int ks = 0; ks < 2; ++ks)
      qf[n][ks] = *(const f16x8*)&q_h[(size_t)(qrow0 + n * 16 + lr) * 1024 + h * 64 + ks * 32 + lg * 8];

  f32x4 accO[4][2];
#pragma unroll
  for (int m = 0; m < 4; ++m) {
    accO[m][0] = (f32x4){0.f, 0.f, 0.f, 0.f};
    accO[m][1] = (f32x4){0.f, 0.f, 0.f, 0.f};
  }
  float mrun[2] = {-1e30f, -1e30f};
  float lrun[2] = {0.f, 0.f};

  for (int kv0 = 0; kv0 < 2048; kv0 += 128) {
#pragma unroll
    for (int r = 0; r < 4; ++r) {
      int off = (tid + r * 256) * 16;
      {  // K tile
        int row = off >> 7;
        int col = ((off & 127) ^ ((row & 7) << 4)) >> 1;
        gload16(&k_h[(size_t)(b * 2048 + kv0 + row) * 1024 + h * 64 + col], (char*)sK + off);
      }
      {  // V^T tile
        int d = off >> 8;
        int col = ((off & 255) ^ ((d & 7) << 4)) >> 1;
        gload16(&v_t[(size_t)(bh * 64 + d) * 2048 + kv0 + col], (char*)sV + off);
      }
    }
    __syncthreads();

    f32x4 st[8][2];
#pragma unroll
    for (int m = 0; m < 8; ++m) {
      st[m][0] = (f32x4){0.f, 0.f, 0.f, 0.f};
      st[m][1] = (f32x4){0.f, 0.f, 0.f, 0.f};
    }
#pragma unroll
    for (int m = 0; m < 8; ++m)
#pragma unroll
      for (int ks = 0; ks < 2; ++ks) {
        int row = m * 16 + lr;
        int koff = (row << 7) + (ks << 6) + (lg << 4);
        koff ^= (row & 7) << 4;
        f16x8 a = *(const f16x8*)((const char*)sK + koff);
        st[m][0] = MFMA16(a, qf[0][ks], st[m][0]);
        st[m][1] = MFMA16(a, qf[1][ks], st[m][1]);
      }

    float fac[2];
#pragma unroll
    for (int n = 0; n < 2; ++n) {
      float vm = -1e30f;
#pragma unroll
      for (int m = 0; m < 8; ++m)
#pragma unroll
        for (int r = 0; r < 4; ++r) vm = fmaxf(vm, st[m][n][r]);
      vm = fmaxf(vm, __shfl_xor(vm, 16));
      vm = fmaxf(vm, __shfl_xor(vm, 32));
      float mnew = fmaxf(mrun[n], vm);
      fac[n] = __expf((mrun[n] - mnew) * 0.125f);
      mrun[n] = mnew;
      float ps = 0.f;
      int q = n * 16 + lr;
#pragma unroll
      for (int m = 0; m < 8; ++m) {
        float p0 = __expf((st[m][n][0] - mnew) * 0.125f);
        float p1 = __expf((st[m][n][1] - mnew) * 0.125f);
        float p2 = __expf((st[m][n][2] - mnew) * 0.125f);
        float p3 = __expf((st[m][n][3] - mnew) * 0.125f);
        ps += p0 + p1 + p2 + p3;
        f16x4 pk;
        pk[0] = (f16)p0; pk[1] = (f16)p1; pk[2] = (f16)p2; pk[3] = (f16)p3;
        int poff = (q << 8) + (m << 5) + (lg << 3);
        poff ^= (q & 7) << 4;
        *(f16x4*)((char*)sP[wave] + poff) = pk;
      }
      ps += __shfl_xor(ps, 16);
      ps += __shfl_xor(ps, 32);
      lrun[n] = lrun[n] * fac[n] + ps;
#pragma unroll
      for (int m = 0; m < 4; ++m) accO[m][n] *= fac[n];
    }
    asm volatile("s_waitcnt lgkmcnt(0)" ::: "memory");
    __builtin_amdgcn_sched_barrier(0);

    f16x8 pb[2][4];
#pragma unroll
    for (int n = 0; n < 2; ++n) {
      int q = n * 16 + lr;
#pragma unroll
      for (int ks = 0; ks < 4; ++ks) {
        int poff = (q << 8) + (ks << 6) + (lg << 4);
        poff ^= (q & 7) << 4;
        pb[n][ks] = *(const f16x8*)((const char*)sP[wave] + poff);
      }
    }
#pragma unroll
    for (int m = 0; m < 4; ++m)
#pragma unroll
      for (int ks = 0; ks < 4; ++ks) {
        int d = m * 16 + lr;
        int voff = (d << 8) + (ks << 6) + (lg << 4);
        voff ^= (d & 7) << 4;
        f16x8 av = *(const f16x8*)((const char*)sV + voff);
        accO[m][0] = MFMA16(av, pb[0][ks], accO[m][0]);
        accO[m][1] = MFMA16(av, pb[1][ks], accO[m][1]);
      }
    __syncthreads();
  }

#pragma unroll
  for (int n = 0; n < 2; ++n) {
    float rl = 1.0f / lrun[n];
    int orow = qrow0 + n * 16 + lr;
#pragma unroll
    for (int m = 0; m < 4; ++m) {
      size_t idx = (size_t)orow * 1024 + h * 64 + m * 16 + lg * 4;
      float4 gv = *(const float4*)&gate_f32[idx];
      f16x4 ov;
      ov[0] = (f16)(accO[m][n][0] * rl / (1.f + __expf(-gv.x)));
      ov[1] = (f16)(accO[m][n][1] * rl / (1.f + __expf(-gv.y)));
      ov[2] = (f16)(accO[m][n][2] * rl / (1.f + __expf(-gv.z)));
      ov[3] = (f16)(accO[m][n][3] * rl / (1.f + __expf(-gv.w)));
      *(f16x4*)&a16[idx] = ov;
    }
  }
}

// ---------------------------------------------------------------------------
extern "C" void kernel_launch(void* const* d_in, const int* in_sizes, int n_in,
                              void* d_out, int out_size, void* d_ws, size_t ws_size,
                              hipStream_t stream) {
  const float* x      = (const float*)d_in[0];
  const float* freqs  = (const float*)d_in[1];
  const float* w_qkv  = (const float*)d_in[2];
  const float* w_out  = (const float*)d_in[3];
  const float* qn_w   = (const float*)d_in[4];
  const float* qn_b   = (const float*)d_in[5];
  const float* kn_w   = (const float*)d_in[6];
  const float* kn_b   = (const float*)d_in[7];
  float* out = (float*)d_out;
  char* ws = (char*)d_ws;
  const size_t MB = 1024 * 1024;
  // ws map (~91 MB used):
  float* q_f32    = (float*)(ws + 0);        // 16 MB
  float* k_f32    = (float*)(ws + 16 * MB);  // 16 MB
  float* gate_f32 = (float*)(ws + 32 * MB);  // 16 MB
  f16*   v_t      = (f16*)(ws + 48 * MB);    // 8 MB  [b,h,d,s]
  f16*   x16      = (f16*)(ws + 56 * MB);    // 8 MB  (x fp16; later aliased by a16)
  f16*   wq16     = (f16*)(ws + 64 * MB);    // 8 MB  w_qkv^T fp16
  f16*   wo16     = (f16*)(ws + 72 * MB);    // 2 MB  w_out^T fp16
  f16*   q_h      = (f16*)(ws + 74 * MB);    // 8 MB
  f16*   k_h      = (f16*)(ws + 82 * MB);    // 8 MB
  float* tbl      = (float*)(ws + 90 * MB);  // 0.5 MB
  f16*   a16      = x16;                     // alias: x dead after GEMM1

  if (ws_size < (size_t)91 * MB) {  // sentinel: signals ws shortfall in absmax
    fill_debug_kernel<<<(out_size + 255) / 256, 256, 0, stream>>>(out, out_size);
    return;
  }

  rope_table_kernel<<<256, 256, 0, stream>>>(freqs, tbl);
  cast_f16_kernel<<<2048, 256, 0, stream>>>(x, x16, 524288);
  transpose_cast_kernel<<<dim3(64, 16), 256, 0, stream>>>(w_qkv, wq16, 1024, 4096);
  transpose_cast_kernel<<<dim3(16, 16), 256, 0, stream>>>(w_out, wo16, 1024, 1024);

  gemm_f16<1><<<dim3(32, 32), 256, 0, stream>>>(x16, wq16, nullptr, 4096, 4096, 1024,
                                                q_f32, k_f32, gate_f32, v_t);
  norm_rope_kernel<<<4096, 256, 0, stream>>>(q_f32, k_f32, tbl, qn_w, qn_b, kn_w, kn_b, q_h, k_h);
  attn_kernel<<<512, 256, 0, stream>>>(q_h, k_h, v_t, gate_f32, a16);
  gemm_f16<0><<<dim3(8, 32), 256, 0, stream>>>(a16, wo16, out, 4096, 1024, 1024,
                                               nullptr, nullptr, nullptr, nullptr);
}